// Round 3
// baseline (598.710 us; speedup 1.0000x reference)
//
#include <hip/hip_runtime.h>
#include <math.h>

#define N_NODES 50000
#define E_EDGES 800000
#define E_TOT   850000   // E_EDGES + N_NODES self loops
#define F_IN    128
#define C1      256      // HEADS*HID
#define NCLS    47
#define H2S     48       // padded stride for H2 (47 -> 48, rows = 3 aligned 64B lines)
#define NEG     0.2f

// ---------------- CSR build ----------------

__global__ void k_count(const int* __restrict__ ei, int* __restrict__ deg) {
    int i = blockIdx.x * 256 + threadIdx.x;
    if (i >= E_TOT) return;
    int dst = (i < E_EDGES) ? ei[E_EDGES + i] : (i - E_EDGES);
    atomicAdd(&deg[dst], 1);
}

// single block, shfl-based scan: row_ptr[i+1] = inclusive prefix, cursor[i] = exclusive
__global__ void k_scan(const int* __restrict__ deg, int* __restrict__ row_ptr,
                       int* __restrict__ cursor) {
    __shared__ int wsum[16];
    int tid = threadIdx.x, lane = tid & 63, w = tid >> 6;
    if (tid == 0) row_ptr[0] = 0;
    int carry = 0;
    for (int base = 0; base < N_NODES; base += 1024) {
        int i = base + tid;
        int v = (i < N_NODES) ? deg[i] : 0;
        int sc = v;                           // inclusive scan within wave
        #pragma unroll
        for (int off = 1; off < 64; off <<= 1) {
            int t = __shfl_up(sc, off);
            if (lane >= off) sc += t;
        }
        if (lane == 63) wsum[w] = sc;
        __syncthreads();
        if (w == 0 && lane < 16) {            // scan the 16 wave totals
            int t = wsum[lane];
            #pragma unroll
            for (int off = 1; off < 16; off <<= 1) {
                int u = __shfl_up(t, off);
                if (lane >= off) t += u;
            }
            wsum[lane] = t;
        }
        __syncthreads();
        int pre = carry + (w > 0 ? wsum[w - 1] : 0) + sc;   // inclusive
        if (i < N_NODES) {
            row_ptr[i + 1] = pre;
            cursor[i]      = pre - v;
        }
        int tot = wsum[15];
        __syncthreads();
        carry += tot;
    }
}

__global__ void k_scatter(const int* __restrict__ ei, int* __restrict__ cursor,
                          int* __restrict__ csr_src) {
    int i = blockIdx.x * 256 + threadIdx.x;
    if (i >= E_TOT) return;
    int src, dst;
    if (i < E_EDGES) { src = ei[i]; dst = ei[E_EDGES + i]; }
    else             { src = dst = i - E_EDGES; }
    int pos = atomicAdd(&cursor[dst], 1);
    csr_src[pos] = src;
}

// ---------------- Layer 1: GEMM (x @ W1) + attention logits ----------------
// one wave per block, 16 rows (halves W1 L2 re-reads vs 8 rows),
// lane owns cols [lane*4, lane*4+4); head = lane>>4.

__global__ void __launch_bounds__(64)
k_gemm1(const float* __restrict__ x, const float* __restrict__ W1,
        const float* __restrict__ a_src1, const float* __restrict__ a_dst1,
        float* __restrict__ H1, float* __restrict__ al_s, float* __restrict__ al_d) {
    __shared__ float xs[16][F_IN];                      // 8 KB
    int n0 = blockIdx.x * 16;
    int lane = threadIdx.x;
    {   // stage 16 rows (2048 floats = 512 float4)
        const float4* xg = (const float4*)(x + (size_t)n0 * F_IN);
        float4* xs4 = (float4*)&xs[0][0];
        #pragma unroll
        for (int j = 0; j < 8; j++) xs4[lane + 64 * j] = xg[lane + 64 * j];
    }
    __syncthreads();
    int c4 = lane * 4;
    float acc[16][4] = {};
    for (int kg = 0; kg < F_IN; kg += 4) {
        float4 w0 = *(const float4*)(W1 + (size_t)(kg + 0) * C1 + c4);
        float4 w1 = *(const float4*)(W1 + (size_t)(kg + 1) * C1 + c4);
        float4 w2 = *(const float4*)(W1 + (size_t)(kg + 2) * C1 + c4);
        float4 w3 = *(const float4*)(W1 + (size_t)(kg + 3) * C1 + c4);
        #pragma unroll
        for (int r = 0; r < 16; r++) {
            float4 xv = *(const float4*)&xs[r][kg];     // wave-uniform broadcast read
            acc[r][0] += xv.x * w0.x + xv.y * w1.x + xv.z * w2.x + xv.w * w3.x;
            acc[r][1] += xv.x * w0.y + xv.y * w1.y + xv.z * w2.y + xv.w * w3.y;
            acc[r][2] += xv.x * w0.z + xv.y * w1.z + xv.z * w2.z + xv.w * w3.z;
            acc[r][3] += xv.x * w0.w + xv.y * w1.w + xv.z * w2.w + xv.w * w3.w;
        }
    }
    int h = lane >> 4;
    int cc4 = (lane & 15) * 4;                          // col within head
    float4 as = *(const float4*)(a_src1 + h * 64 + cc4);
    float4 ad = *(const float4*)(a_dst1 + h * 64 + cc4);
    #pragma unroll
    for (int r = 0; r < 16; r++) {
        int n = n0 + r;
        *(float4*)(H1 + (size_t)n * C1 + c4) =
            make_float4(acc[r][0], acc[r][1], acc[r][2], acc[r][3]);
        float vs = acc[r][0]*as.x + acc[r][1]*as.y + acc[r][2]*as.z + acc[r][3]*as.w;
        float vd = acc[r][0]*ad.x + acc[r][1]*ad.y + acc[r][2]*ad.z + acc[r][3]*ad.w;
        #pragma unroll
        for (int off = 8; off; off >>= 1) {             // reduce within 16-lane head group
            vs += __shfl_xor(vs, off);
            vd += __shfl_xor(vd, off);
        }
        if ((lane & 15) == 0) {
            al_s[n * 4 + h] = vs;
            al_d[n * 4 + h] = vd;
        }
    }
}

// ---------------- Layer 1 aggregation: online softmax, one wave per node ----------------
// lane owns channels [lane*4, lane*4+4); head = lane>>4. 2-edge unroll.
// L3-BW-bound: 850K edges x 1KB H1 row gather ~= 870 MB from Infinity Cache.

__global__ void k_agg1(const float* __restrict__ H1, const float* __restrict__ al_s,
                       const float* __restrict__ al_d, const int* __restrict__ row_ptr,
                       const int* __restrict__ csr_src, const float* __restrict__ b1,
                       float* __restrict__ HE) {
    int n = blockIdx.x * 4 + (threadIdx.x >> 6);
    int lane = threadIdx.x & 63;
    int h = lane >> 4;
    int beg = row_ptr[n], end = row_ptr[n + 1];
    float ald = al_d[n * 4 + h];
    float m = -INFINITY, s = 0.f;
    float a0 = 0.f, a1 = 0.f, a2 = 0.f, a3 = 0.f;
    int j = beg;
    for (; j + 1 < end; j += 2) {
        int s0 = csr_src[j], s1 = csr_src[j + 1];
        float es0 = al_s[s0 * 4 + h], es1 = al_s[s1 * 4 + h];
        float4 h0 = *(const float4*)(H1 + (size_t)s0 * C1 + lane * 4);
        float4 h1 = *(const float4*)(H1 + (size_t)s1 * C1 + lane * 4);
        float e0 = es0 + ald; e0 = (e0 >= 0.f) ? e0 : NEG * e0;
        float e1 = es1 + ald; e1 = (e1 >= 0.f) ? e1 : NEG * e1;
        float nm = fmaxf(m, fmaxf(e0, e1));
        float f  = __expf(m - nm);
        float p0 = __expf(e0 - nm);
        float p1 = __expf(e1 - nm);
        s  = s  * f + p0 + p1;
        a0 = a0 * f + p0 * h0.x + p1 * h1.x;
        a1 = a1 * f + p0 * h0.y + p1 * h1.y;
        a2 = a2 * f + p0 * h0.z + p1 * h1.z;
        a3 = a3 * f + p0 * h0.w + p1 * h1.w;
        m = nm;
    }
    if (j < end) {
        int s0 = csr_src[j];
        float e = al_s[s0 * 4 + h] + ald;
        e = (e >= 0.f) ? e : NEG * e;
        float4 h0 = *(const float4*)(H1 + (size_t)s0 * C1 + lane * 4);
        float nm = fmaxf(m, e);
        float f  = __expf(m - nm);
        float pr = __expf(e - nm);
        s  = s  * f + pr;
        a0 = a0 * f + pr * h0.x;
        a1 = a1 * f + pr * h0.y;
        a2 = a2 * f + pr * h0.z;
        a3 = a3 * f + pr * h0.w;
    }
    float inv = 1.f / (s + 1e-16f);
    float4 bb = *(const float4*)(b1 + lane * 4);
    float o0 = a0 * inv + bb.x, o1 = a1 * inv + bb.y;
    float o2 = a2 * inv + bb.z, o3 = a3 * inv + bb.w;
    o0 = (o0 > 0.f) ? o0 : expm1f(o0);
    o1 = (o1 > 0.f) ? o1 : expm1f(o1);
    o2 = (o2 > 0.f) ? o2 : expm1f(o2);
    o3 = (o3 > 0.f) ? o3 : expm1f(o3);
    *(float4*)(HE + (size_t)n * C1 + lane * 4) = make_float4(o0, o1, o2, o3);
}

// ---------------- Layer 2: GEMM (HE @ W2) + logits ----------------
// one wave per block, 16 rows; lane<47 owns one output column. H2 padded stride 48.

__global__ void __launch_bounds__(64)
k_gemm2(const float* __restrict__ HE, const float* __restrict__ W2,
        const float* __restrict__ a_src2, const float* __restrict__ a_dst2,
        float* __restrict__ H2, float* __restrict__ al_s2, float* __restrict__ al_d2) {
    __shared__ float hs[16][C1];                        // 16 KB
    int n0 = blockIdx.x * 16;
    int lane = threadIdx.x;
    {   // stage 16 rows (4096 floats = 1024 float4)
        const float4* hg = (const float4*)(HE + (size_t)n0 * C1);
        float4* hs4 = (float4*)&hs[0][0];
        #pragma unroll
        for (int j = 0; j < 16; j++) hs4[lane + 64 * j] = hg[lane + 64 * j];
    }
    __syncthreads();
    bool act = lane < NCLS;
    float acc[16] = {};
    for (int kg = 0; kg < C1; kg += 4) {
        float w0 = act ? W2[(size_t)(kg + 0) * NCLS + lane] : 0.f;
        float w1 = act ? W2[(size_t)(kg + 1) * NCLS + lane] : 0.f;
        float w2 = act ? W2[(size_t)(kg + 2) * NCLS + lane] : 0.f;
        float w3 = act ? W2[(size_t)(kg + 3) * NCLS + lane] : 0.f;
        #pragma unroll
        for (int r = 0; r < 16; r++) {
            float4 hv = *(const float4*)&hs[r][kg];     // wave-uniform broadcast read
            acc[r] += hv.x * w0 + hv.y * w1 + hv.z * w2 + hv.w * w3;
        }
    }
    float as = act ? a_src2[lane] : 0.f;
    float ad = act ? a_dst2[lane] : 0.f;
    #pragma unroll
    for (int r = 0; r < 16; r++) {
        int n = n0 + r;
        float vs = acc[r] * as, vd = acc[r] * ad;
        #pragma unroll
        for (int off = 32; off; off >>= 1) {
            vs += __shfl_xor(vs, off);
            vd += __shfl_xor(vd, off);
        }
        if (act) H2[(size_t)n * H2S + lane] = acc[r];
        if (lane == 0) { al_s2[n] = vs; al_d2[n] = vd; }
    }
}

// ---------------- Layer 2 aggregation + bias + log_softmax ----------------
// one wave per node; lane<47 owns a class.

__global__ void k_agg2(const float* __restrict__ H2, const float* __restrict__ al_s2,
                       const float* __restrict__ al_d2, const int* __restrict__ row_ptr,
                       const int* __restrict__ csr_src, const float* __restrict__ b2,
                       float* __restrict__ out) {
    int n = blockIdx.x * 4 + (threadIdx.x >> 6);
    if (n >= N_NODES) return;
    int lane = threadIdx.x & 63;
    int beg = row_ptr[n], end = row_ptr[n + 1];
    float ald = al_d2[n];
    float m = -INFINITY, s = 0.f, acc = 0.f;
    for (int j = beg; j < end; j++) {
        int src = csr_src[j];
        float e = al_s2[src] + ald;
        e = (e >= 0.f) ? e : NEG * e;
        float nm = fmaxf(m, e);
        float f  = __expf(m - nm);
        float pr = __expf(e - nm);
        s = s * f + pr;
        float hv = (lane < NCLS) ? H2[(size_t)src * H2S + lane] : 0.f;
        acc = acc * f + pr * hv;
        m = nm;
    }
    float v = acc / (s + 1e-16f) + ((lane < NCLS) ? b2[lane] : -INFINITY);
    float mx = v;
    #pragma unroll
    for (int off = 32; off; off >>= 1) mx = fmaxf(mx, __shfl_xor(mx, off));
    float ex = __expf(v - mx);            // lanes >= 47 contribute 0
    float sum = ex;
    #pragma unroll
    for (int off = 32; off; off >>= 1) sum += __shfl_xor(sum, off);
    if (lane < NCLS) out[(size_t)n * NCLS + lane] = v - mx - logf(sum);
}

// ---------------- host ----------------

extern "C" void kernel_launch(void* const* d_in, const int* in_sizes, int n_in,
                              void* d_out, int out_size, void* d_ws, size_t ws_size,
                              hipStream_t stream) {
    const float* x      = (const float*)d_in[0];
    const int*   ei     = (const int*)  d_in[1];
    const float* W1     = (const float*)d_in[2];
    const float* a_src1 = (const float*)d_in[3];
    const float* a_dst1 = (const float*)d_in[4];
    const float* b1     = (const float*)d_in[5];
    const float* W2     = (const float*)d_in[6];
    const float* a_src2 = (const float*)d_in[7];
    const float* a_dst2 = (const float*)d_in[8];
    const float* b2     = (const float*)d_in[9];
    float* out = (float*)d_out;

    char* base = (char*)d_ws;
    size_t off = 0;
    auto alloc = [&](size_t bytes) -> void* {
        void* r = base + off;
        off += (bytes + 511) & ~size_t(511);
        return r;
    };
    float* H1     = (float*)alloc((size_t)N_NODES * C1 * 4);
    float* HE     = (float*)alloc((size_t)N_NODES * C1 * 4);
    float* H2     = (float*)alloc((size_t)N_NODES * H2S * 4);
    float* al_s1  = (float*)alloc((size_t)N_NODES * 4 * 4);
    float* al_d1  = (float*)alloc((size_t)N_NODES * 4 * 4);
    float* al_s2  = (float*)alloc((size_t)N_NODES * 4);
    float* al_d2  = (float*)alloc((size_t)N_NODES * 4);
    int*   deg    = (int*)  alloc((size_t)N_NODES * 4);
    int*   rowp   = (int*)  alloc((size_t)(N_NODES + 1) * 4);
    int*   cursor = (int*)  alloc((size_t)N_NODES * 4);
    int*   csrs   = (int*)  alloc((size_t)E_TOT * 4);

    hipMemsetAsync(deg, 0, (size_t)N_NODES * 4, stream);

    int eb = (E_TOT + 255) / 256;
    k_count  <<<eb, 256, 0, stream>>>(ei, deg);
    k_scan   <<<1, 1024, 0, stream>>>(deg, rowp, cursor);
    k_scatter<<<eb, 256, 0, stream>>>(ei, cursor, csrs);

    k_gemm1<<<N_NODES / 16, 64, 0, stream>>>(x, W1, a_src1, a_dst1, H1, al_s1, al_d1);
    k_agg1 <<<(N_NODES + 3) / 4, 256, 0, stream>>>(H1, al_s1, al_d1, rowp, csrs, b1, HE);
    k_gemm2<<<N_NODES / 16, 64, 0, stream>>>(HE, W2, a_src2, a_dst2, H2, al_s2, al_d2);
    k_agg2 <<<(N_NODES + 3) / 4, 256, 0, stream>>>(H2, al_s2, al_d2, rowp, csrs, b2, out);
}

// Round 6
// 493.799 us; speedup vs baseline: 1.2125x; 1.2125x over previous
//
#include <hip/hip_runtime.h>
#include <hip/hip_fp16.h>
#include <math.h>

#define N_NODES 50000
#define E_EDGES 800000
#define E_TOT   850000   // E_EDGES + N_NODES self loops
#define F_IN    128
#define C1      256      // HEADS*HID
#define NCLS    47
#define H2S     48       // padded stride for H2 (47 -> 48)
#define NEG     0.2f
#define SCAN_B  196      // ceil(50000/256)

// ---------------- CSR build ----------------

__global__ void k_count(const int* __restrict__ ei, int* __restrict__ deg) {
    int i = blockIdx.x * 256 + threadIdx.x;
    if (i >= E_TOT) return;
    int dst = (i < E_EDGES) ? ei[E_EDGES + i] : (i - E_EDGES);
    atomicAdd(&deg[dst], 1);
}

// pass 1: per-block sums of deg
__global__ void k_scan_blk(const int* __restrict__ deg, int* __restrict__ blksum) {
    __shared__ int ws[4];
    int i = blockIdx.x * 256 + threadIdx.x;
    int v = (i < N_NODES) ? deg[i] : 0;
    int lane = threadIdx.x & 63, w = threadIdx.x >> 6;
    #pragma unroll
    for (int off = 32; off; off >>= 1) v += __shfl_xor(v, off);
    if (lane == 0) ws[w] = v;
    __syncthreads();
    if (threadIdx.x == 0) blksum[blockIdx.x] = ws[0] + ws[1] + ws[2] + ws[3];
}

// pass 2: single block exclusive-scans the SCAN_B block sums
__global__ void k_scan_top(const int* __restrict__ blksum, int* __restrict__ blkoff) {
    __shared__ int ws[4];
    int tid = threadIdx.x, lane = tid & 63, w = tid >> 6;
    int v = (tid < SCAN_B) ? blksum[tid] : 0;
    int sc = v;
    #pragma unroll
    for (int off = 1; off < 64; off <<= 1) {
        int t = __shfl_up(sc, off);
        if (lane >= off) sc += t;
    }
    if (lane == 63) ws[w] = sc;
    __syncthreads();
    if (tid == 0) { int a = 0; for (int t = 0; t < 4; t++) { int u = ws[t]; ws[t] = a; a += u; } }
    __syncthreads();
    if (tid < SCAN_B) blkoff[tid] = sc + ws[w] - v;   // exclusive
}

// pass 3: local scan + block offset -> row_ptr / cursor
__global__ void k_scan_fin(const int* __restrict__ deg, const int* __restrict__ blkoff,
                           int* __restrict__ row_ptr, int* __restrict__ cursor) {
    __shared__ int ws[4];
    int i = blockIdx.x * 256 + threadIdx.x;
    int v = (i < N_NODES) ? deg[i] : 0;
    int lane = threadIdx.x & 63, w = threadIdx.x >> 6;
    int sc = v;
    #pragma unroll
    for (int off = 1; off < 64; off <<= 1) {
        int t = __shfl_up(sc, off);
        if (lane >= off) sc += t;
    }
    if (lane == 63) ws[w] = sc;
    __syncthreads();
    if (threadIdx.x == 0) { int a = 0; for (int t = 0; t < 4; t++) { int u = ws[t]; ws[t] = a; a += u; } }
    __syncthreads();
    int incl = sc + ws[w] + blkoff[blockIdx.x];
    if (i < N_NODES) {
        row_ptr[i + 1] = incl;
        cursor[i]      = incl - v;
    }
    if (i == 0) row_ptr[0] = 0;
}

__global__ void k_scatter(const int* __restrict__ ei, int* __restrict__ cursor,
                          int* __restrict__ csr_src) {
    int i = blockIdx.x * 256 + threadIdx.x;
    if (i >= E_TOT) return;
    int src, dst;
    if (i < E_EDGES) { src = ei[i]; dst = ei[E_EDGES + i]; }
    else             { src = dst = i - E_EDGES; }
    int pos = atomicAdd(&cursor[dst], 1);
    csr_src[pos] = src;
}

// ---------------- Layer 1: GEMM (x @ W1) + attention logits ----------------
// one wave per block, 16 rows; lane owns cols [lane*4, lane*4+4); head = lane>>4.
// H1 stored fp16 (gather payload only; logits from fp32 acc).

__global__ void __launch_bounds__(64)
k_gemm1(const float* __restrict__ x, const float* __restrict__ W1,
        const float* __restrict__ a_src1, const float* __restrict__ a_dst1,
        __half* __restrict__ H1h, float* __restrict__ al_s, float* __restrict__ al_d) {
    __shared__ float xs[16][F_IN];                      // 8 KB
    int n0 = blockIdx.x * 16;
    int lane = threadIdx.x;
    {
        const float4* xg = (const float4*)(x + (size_t)n0 * F_IN);
        float4* xs4 = (float4*)&xs[0][0];
        #pragma unroll
        for (int j = 0; j < 8; j++) xs4[lane + 64 * j] = xg[lane + 64 * j];
    }
    __syncthreads();
    int c4 = lane * 4;
    float acc[16][4] = {};
    for (int kg = 0; kg < F_IN; kg += 4) {
        float4 w0 = *(const float4*)(W1 + (size_t)(kg + 0) * C1 + c4);
        float4 w1 = *(const float4*)(W1 + (size_t)(kg + 1) * C1 + c4);
        float4 w2 = *(const float4*)(W1 + (size_t)(kg + 2) * C1 + c4);
        float4 w3 = *(const float4*)(W1 + (size_t)(kg + 3) * C1 + c4);
        #pragma unroll
        for (int r = 0; r < 16; r++) {
            float4 xv = *(const float4*)&xs[r][kg];     // wave-uniform broadcast
            acc[r][0] += xv.x * w0.x + xv.y * w1.x + xv.z * w2.x + xv.w * w3.x;
            acc[r][1] += xv.x * w0.y + xv.y * w1.y + xv.z * w2.y + xv.w * w3.y;
            acc[r][2] += xv.x * w0.z + xv.y * w1.z + xv.z * w2.z + xv.w * w3.z;
            acc[r][3] += xv.x * w0.w + xv.y * w1.w + xv.z * w2.w + xv.w * w3.w;
        }
    }
    int h = lane >> 4;
    int cc4 = (lane & 15) * 4;
    float4 as = *(const float4*)(a_src1 + h * 64 + cc4);
    float4 ad = *(const float4*)(a_dst1 + h * 64 + cc4);
    #pragma unroll
    for (int r = 0; r < 16; r++) {
        int n = n0 + r;
        ushort4 pk;
        pk.x = __half_as_ushort(__float2half_rn(acc[r][0]));
        pk.y = __half_as_ushort(__float2half_rn(acc[r][1]));
        pk.z = __half_as_ushort(__float2half_rn(acc[r][2]));
        pk.w = __half_as_ushort(__float2half_rn(acc[r][3]));
        *(ushort4*)(H1h + (size_t)n * C1 + c4) = pk;
        float vs = acc[r][0]*as.x + acc[r][1]*as.y + acc[r][2]*as.z + acc[r][3]*as.w;
        float vd = acc[r][0]*ad.x + acc[r][1]*ad.y + acc[r][2]*ad.z + acc[r][3]*ad.w;
        #pragma unroll
        for (int off = 8; off; off >>= 1) {
            vs += __shfl_xor(vs, off);
            vd += __shfl_xor(vd, off);
        }
        if ((lane & 15) == 0) {
            al_s[n * 4 + h] = vs;
            al_d[n * 4 + h] = vd;
        }
    }
}

// ---------------- Layer 1 aggregation: online softmax, one wave per node ----------------
// fp16 rows (512B), 4-edge unroll keeps ~2KB/wave in flight.

__global__ void k_agg1(const __half* __restrict__ H1h, const float* __restrict__ al_s,
                       const float* __restrict__ al_d, const int* __restrict__ row_ptr,
                       const int* __restrict__ csr_src, const float* __restrict__ b1,
                       float* __restrict__ HE) {
    int n = blockIdx.x * 4 + (threadIdx.x >> 6);
    int lane = threadIdx.x & 63;
    int h = lane >> 4;
    int beg = row_ptr[n], end = row_ptr[n + 1];
    float ald = al_d[n * 4 + h];
    float m = -INFINITY, s = 0.f;
    float a0 = 0.f, a1 = 0.f, a2 = 0.f, a3 = 0.f;
    int j = beg;
    for (; j + 3 < end; j += 4) {
        int ss[4]; float ee[4]; ushort4 hh[4];
        #pragma unroll
        for (int t = 0; t < 4; t++) ss[t] = csr_src[j + t];
        #pragma unroll
        for (int t = 0; t < 4; t++) ee[t] = al_s[ss[t] * 4 + h];
        #pragma unroll
        for (int t = 0; t < 4; t++)
            hh[t] = *(const ushort4*)(H1h + (size_t)ss[t] * C1 + lane * 4);
        #pragma unroll
        for (int t = 0; t < 4; t++) {
            float e = ee[t] + ald;
            ee[t] = (e >= 0.f) ? e : NEG * e;
        }
        float nm = fmaxf(m, fmaxf(fmaxf(ee[0], ee[1]), fmaxf(ee[2], ee[3])));
        float f = __expf(m - nm);
        m = nm;
        float p[4];
        #pragma unroll
        for (int t = 0; t < 4; t++) p[t] = __expf(ee[t] - nm);
        s = s * f + p[0] + p[1] + p[2] + p[3];
        a0 *= f; a1 *= f; a2 *= f; a3 *= f;
        #pragma unroll
        for (int t = 0; t < 4; t++) {
            a0 += p[t] * __half2float(__ushort_as_half(hh[t].x));
            a1 += p[t] * __half2float(__ushort_as_half(hh[t].y));
            a2 += p[t] * __half2float(__ushort_as_half(hh[t].z));
            a3 += p[t] * __half2float(__ushort_as_half(hh[t].w));
        }
    }
    for (; j < end; j++) {
        int s0 = csr_src[j];
        float e = al_s[s0 * 4 + h] + ald;
        e = (e >= 0.f) ? e : NEG * e;
        ushort4 hv = *(const ushort4*)(H1h + (size_t)s0 * C1 + lane * 4);
        float nm = fmaxf(m, e);
        float f  = __expf(m - nm);
        float pr = __expf(e - nm);
        s  = s  * f + pr;
        a0 = a0 * f + pr * __half2float(__ushort_as_half(hv.x));
        a1 = a1 * f + pr * __half2float(__ushort_as_half(hv.y));
        a2 = a2 * f + pr * __half2float(__ushort_as_half(hv.z));
        a3 = a3 * f + pr * __half2float(__ushort_as_half(hv.w));
        m = nm;
    }
    float inv = 1.f / (s + 1e-16f);
    float4 bb = *(const float4*)(b1 + lane * 4);
    float o0 = a0 * inv + bb.x, o1 = a1 * inv + bb.y;
    float o2 = a2 * inv + bb.z, o3 = a3 * inv + bb.w;
    o0 = (o0 > 0.f) ? o0 : expm1f(o0);
    o1 = (o1 > 0.f) ? o1 : expm1f(o1);
    o2 = (o2 > 0.f) ? o2 : expm1f(o2);
    o3 = (o3 > 0.f) ? o3 : expm1f(o3);
    *(float4*)(HE + (size_t)n * C1 + lane * 4) = make_float4(o0, o1, o2, o3);
}

// ---------------- Layer 2: GEMM (HE @ W2) + logits ----------------
// one wave per block, 16 rows; lane<47 owns one output column. H2 fp16, stride 48.

__global__ void __launch_bounds__(64)
k_gemm2(const float* __restrict__ HE, const float* __restrict__ W2,
        const float* __restrict__ a_src2, const float* __restrict__ a_dst2,
        __half* __restrict__ H2h, float* __restrict__ al_s2, float* __restrict__ al_d2) {
    __shared__ float hs[16][C1];                        // 16 KB
    int n0 = blockIdx.x * 16;
    int lane = threadIdx.x;
    {
        const float4* hg = (const float4*)(HE + (size_t)n0 * C1);
        float4* hs4 = (float4*)&hs[0][0];
        #pragma unroll
        for (int j = 0; j < 16; j++) hs4[lane + 64 * j] = hg[lane + 64 * j];
    }
    __syncthreads();
    bool act = lane < NCLS;
    float acc[16] = {};
    for (int kg = 0; kg < C1; kg += 4) {
        float w0 = act ? W2[(size_t)(kg + 0) * NCLS + lane] : 0.f;
        float w1 = act ? W2[(size_t)(kg + 1) * NCLS + lane] : 0.f;
        float w2 = act ? W2[(size_t)(kg + 2) * NCLS + lane] : 0.f;
        float w3 = act ? W2[(size_t)(kg + 3) * NCLS + lane] : 0.f;
        #pragma unroll
        for (int r = 0; r < 16; r++) {
            float4 hv = *(const float4*)&hs[r][kg];     // wave-uniform broadcast
            acc[r] += hv.x * w0 + hv.y * w1 + hv.z * w2 + hv.w * w3;
        }
    }
    float as = act ? a_src2[lane] : 0.f;
    float ad = act ? a_dst2[lane] : 0.f;
    #pragma unroll
    for (int r = 0; r < 16; r++) {
        int n = n0 + r;
        float vs = acc[r] * as, vd = acc[r] * ad;
        #pragma unroll
        for (int off = 32; off; off >>= 1) {
            vs += __shfl_xor(vs, off);
            vd += __shfl_xor(vd, off);
        }
        if (act) H2h[(size_t)n * H2S + lane] = __float2half_rn(acc[r]);
        if (lane == 0) { al_s2[n] = vs; al_d2[n] = vd; }
    }
}

// ---------------- Layer 2 aggregation + bias + log_softmax ----------------

__global__ void k_agg2(const __half* __restrict__ H2h, const float* __restrict__ al_s2,
                       const float* __restrict__ al_d2, const int* __restrict__ row_ptr,
                       const int* __restrict__ csr_src, const float* __restrict__ b2,
                       float* __restrict__ out) {
    int n = blockIdx.x * 4 + (threadIdx.x >> 6);
    if (n >= N_NODES) return;
    int lane = threadIdx.x & 63;
    int beg = row_ptr[n], end = row_ptr[n + 1];
    float ald = al_d2[n];
    float m = -INFINITY, s = 0.f, acc = 0.f;
    for (int j = beg; j < end; j++) {
        int src = csr_src[j];
        float e = al_s2[src] + ald;
        e = (e >= 0.f) ? e : NEG * e;
        float nm = fmaxf(m, e);
        float f  = __expf(m - nm);
        float pr = __expf(e - nm);
        s = s * f + pr;
        float hv = (lane < NCLS) ? __half2float(H2h[(size_t)src * H2S + lane]) : 0.f;
        acc = acc * f + pr * hv;
        m = nm;
    }
    float v = acc / (s + 1e-16f) + ((lane < NCLS) ? b2[lane] : -INFINITY);
    float mx = v;
    #pragma unroll
    for (int off = 32; off; off >>= 1) mx = fmaxf(mx, __shfl_xor(mx, off));
    float ex = __expf(v - mx);            // lanes >= 47 contribute 0
    float sum = ex;
    #pragma unroll
    for (int off = 32; off; off >>= 1) sum += __shfl_xor(sum, off);
    if (lane < NCLS) out[(size_t)n * NCLS + lane] = v - mx - logf(sum);
}

// ---------------- host ----------------

extern "C" void kernel_launch(void* const* d_in, const int* in_sizes, int n_in,
                              void* d_out, int out_size, void* d_ws, size_t ws_size,
                              hipStream_t stream) {
    const float* x      = (const float*)d_in[0];
    const int*   ei     = (const int*)  d_in[1];
    const float* W1     = (const float*)d_in[2];
    const float* a_src1 = (const float*)d_in[3];
    const float* a_dst1 = (const float*)d_in[4];
    const float* b1     = (const float*)d_in[5];
    const float* W2     = (const float*)d_in[6];
    const float* a_src2 = (const float*)d_in[7];
    const float* a_dst2 = (const float*)d_in[8];
    const float* b2     = (const float*)d_in[9];
    float* out = (float*)d_out;

    char* base = (char*)d_ws;
    size_t off = 0;
    auto alloc = [&](size_t bytes) -> void* {
        void* r = base + off;
        off += (bytes + 511) & ~size_t(511);
        return r;
    };
    __half* H1h   = (__half*)alloc((size_t)N_NODES * C1 * 2);
    float*  HE    = (float*) alloc((size_t)N_NODES * C1 * 4);
    __half* H2h   = (__half*)alloc((size_t)N_NODES * H2S * 2);
    float*  al_s1 = (float*) alloc((size_t)N_NODES * 4 * 4);
    float*  al_d1 = (float*) alloc((size_t)N_NODES * 4 * 4);
    float*  al_s2 = (float*) alloc((size_t)N_NODES * 4);
    float*  al_d2 = (float*) alloc((size_t)N_NODES * 4);
    int*    deg   = (int*)   alloc((size_t)N_NODES * 4);
    int*    rowp  = (int*)   alloc((size_t)(N_NODES + 1) * 4);
    int*    cursor= (int*)   alloc((size_t)N_NODES * 4);
    int*    blks  = (int*)   alloc((size_t)SCAN_B * 4);
    int*    blko  = (int*)   alloc((size_t)SCAN_B * 4);
    int*    csrs  = (int*)   alloc((size_t)E_TOT * 4);

    hipMemsetAsync(deg, 0, (size_t)N_NODES * 4, stream);

    int eb = (E_TOT + 255) / 256;
    k_count   <<<eb, 256, 0, stream>>>(ei, deg);
    k_scan_blk<<<SCAN_B, 256, 0, stream>>>(deg, blks);
    k_scan_top<<<1, 256, 0, stream>>>(blks, blko);
    k_scan_fin<<<SCAN_B, 256, 0, stream>>>(deg, blko, rowp, cursor);
    k_scatter <<<eb, 256, 0, stream>>>(ei, cursor, csrs);

    k_gemm1<<<N_NODES / 16, 64, 0, stream>>>(x, W1, a_src1, a_dst1, H1h, al_s1, al_d1);
    k_agg1 <<<(N_NODES + 3) / 4, 256, 0, stream>>>(H1h, al_s1, al_d1, rowp, csrs, b1, HE);
    k_gemm2<<<N_NODES / 16, 64, 0, stream>>>(HE, W2, a_src2, a_dst2, H2h, al_s2, al_d2);
    k_agg2 <<<(N_NODES + 3) / 4, 256, 0, stream>>>(H2h, al_s2, al_d2, rowp, csrs, b2, out);
}